// Round 1
// baseline (191.350 us; speedup 1.0000x reference)
//
#include <hip/hip_runtime.h>
#include <hip/hip_bf16.h>
#include <stdint.h>

#define B_  2
#define S_  2048
#define D_  1024
#define H_  16
#define HD_ 64

typedef __attribute__((ext_vector_type(8))) __bf16 bf16x8;
typedef __attribute__((ext_vector_type(4))) __bf16 bf16x4;
typedef __attribute__((ext_vector_type(4))) float  f32x4;

__device__ __forceinline__ __bf16 f2bf(float f) {
  union { float f; uint32_t u; } v; v.f = f;
  uint32_t r = v.u + 0x7FFF + ((v.u >> 16) & 1);
  unsigned short h = (unsigned short)(r >> 16);
  return __builtin_bit_cast(__bf16, h);
}

__device__ __forceinline__ void gload16(const void* g, void* l) {
  __builtin_amdgcn_global_load_lds(
      (__attribute__((address_space(1))) void*)(uintptr_t)g,
      (__attribute__((address_space(3))) void*)(uintptr_t)l,
      16, 0, 0);
}

// ---------------- zero output ----------------
__global__ __launch_bounds__(256) void zero_out_k(float* out) {
  int i = blockIdx.x * 256 + threadIdx.x;
  if (i < B_ * D_) out[i] = 0.0f;
}

// ---------------- X fp32 -> bf16 ----------------
__global__ __launch_bounds__(256) void convert_x(const float* __restrict__ x,
                                                 __bf16* __restrict__ xb) {
  int i = blockIdx.x * 256 + threadIdx.x;  // one float4 per thread
  float4 v = ((const float4*)x)[i];
  bf16x4 o;
  o[0] = f2bf(v.x); o[1] = f2bf(v.y); o[2] = f2bf(v.z); o[3] = f2bf(v.w);
  ((bf16x4*)xb)[i] = o;
}

// ---------------- W [k][n] fp32 -> Wt [n][k] bf16 (x3) ----------------
__global__ __launch_bounds__(256) void transpose_w(const float* __restrict__ wq,
                                                   const float* __restrict__ wk,
                                                   const float* __restrict__ wv,
                                                   __bf16* __restrict__ wt) {
  __shared__ float tile[32][33];
  const float* w = (blockIdx.z == 0) ? wq : (blockIdx.z == 1 ? wk : wv);
  __bf16* o = wt + (size_t)blockIdx.z * D_ * D_;
  int k0 = blockIdx.y * 32, n0 = blockIdx.x * 32;
  int tx = threadIdx.x, ty = threadIdx.y;
  for (int i = 0; i < 4; ++i)
    tile[ty + 8 * i][tx] = w[(size_t)(k0 + ty + 8 * i) * D_ + n0 + tx];
  __syncthreads();
  for (int i = 0; i < 4; ++i)
    o[(size_t)(n0 + ty + 8 * i) * D_ + k0 + tx] = f2bf(tile[tx][ty + 8 * i]);
}

// ---------------- QKV GEMM: C[4096,1024] = Xb @ Wt^T, scatter epilogue ----------------
// z=0 -> Q [B,H,S,HD]; z=1 -> K [B,H,S,HD]; z=2 -> V^T [B,H,HD,S]
__global__ __launch_bounds__(256, 2) void gemm_qkv(
    const __bf16* __restrict__ xb, const __bf16* __restrict__ wt,
    const float* __restrict__ bq, const float* __restrict__ bk,
    const float* __restrict__ bv, __bf16* __restrict__ qh,
    __bf16* __restrict__ kh, __bf16* __restrict__ vt) {
  constexpr int K = 1024;
  __shared__ __attribute__((aligned(16))) __bf16 lA[128 * 32];
  __shared__ __attribute__((aligned(16))) __bf16 lB[128 * 32];

  const int z = blockIdx.z;
  const __bf16* w = wt + (size_t)z * K * D_;
  const float* bias = (z == 0) ? bq : (z == 1 ? bk : bv);
  const int t = threadIdx.x;
  const int lane = t & 63;
  const int wid = t >> 6;
  const int quad = lane >> 4;
  const int col = lane & 15;
  const int m0 = blockIdx.y * 128;
  const int n0 = blockIdx.x * 128;
  const int wr = (wid >> 1) * 64;
  const int wc = (wid & 1) * 64;

  // staging: row = r2*64 + (t>>2); LDS slot chunk = t&3 holds global chunk gc
  const int srow = t >> 2;
  const int gc = (t & 3) ^ ((t >> 3) & 3);

  f32x4 acc[4][4] = {};

  for (int kt = 0; kt < K / 32; ++kt) {
    __syncthreads();
    for (int r2 = 0; r2 < 2; ++r2) {
      int row = r2 * 64 + srow;
      gload16(xb + (size_t)(m0 + row) * K + kt * 32 + gc * 8,
              (char*)lA + row * 64 + (t & 3) * 16);
      gload16(w + (size_t)(n0 + row) * K + kt * 32 + gc * 8,
              (char*)lB + row * 64 + (t & 3) * 16);
    }
    __syncthreads();

    bf16x8 afrag[4], bfrag[4];
    for (int mi = 0; mi < 4; ++mi) {
      int m = wr + mi * 16 + col;
      int ch = quad ^ ((m >> 1) & 3);
      afrag[mi] = *(const bf16x8*)((const char*)lA + m * 64 + ch * 16);
    }
    for (int ni = 0; ni < 4; ++ni) {
      int n = wc + ni * 16 + col;
      int ch = quad ^ ((n >> 1) & 3);
      bfrag[ni] = *(const bf16x8*)((const char*)lB + n * 64 + ch * 16);
    }
    for (int mi = 0; mi < 4; ++mi)
      for (int ni = 0; ni < 4; ++ni)
        acc[mi][ni] = __builtin_amdgcn_mfma_f32_16x16x32_bf16(
            afrag[mi], bfrag[ni], acc[mi][ni], 0, 0, 0);
  }

  // epilogue: C row=(lane>>4)*4+reg, col=lane&15  [verified m89/m91]
  for (int mi = 0; mi < 4; ++mi) {
    for (int ni = 0; ni < 4; ++ni) {
      int gn = n0 + wc + ni * 16 + col;
      float bi = bias[gn];
      int h = gn >> 6, hd = gn & 63;
      for (int r = 0; r < 4; ++r) {
        int gm = m0 + wr + mi * 16 + quad * 4 + r;
        int b = gm >> 11, s = gm & 2047;
        float v = acc[mi][ni][r] + bi;
        if (z < 2) {
          __bf16* dst = (z == 0) ? qh : kh;
          dst[((size_t)(b * H_ + h) * S_ + s) * HD_ + hd] = f2bf(v);
        } else {
          vt[((size_t)(b * H_ + h) * HD_ + hd) * S_ + s] = f2bf(v);
        }
      }
    }
  }
}

// ---------------- fused attention + mean pool ----------------
// grid (S/128, B*H), 256 threads (4 waves). Wave w owns q-rows [blk*128+w*32, +32).
__global__ __launch_bounds__(256, 2) void attn(const __bf16* __restrict__ qh,
                                               const __bf16* __restrict__ kh,
                                               const __bf16* __restrict__ vt,
                                               float* __restrict__ out) {
  __shared__ __attribute__((aligned(16))) __bf16 lK[128 * 64];      // [s_k][hd] swizzled
  __shared__ __attribute__((aligned(16))) __bf16 lV[64 * 128];      // [hd][s_k] swizzled
  __shared__ __attribute__((aligned(16))) __bf16 lP[4][32 * 128];   // per-wave P, swizzled

  const int t = threadIdx.x;
  const int lane = t & 63;
  const int wid = t >> 6;
  const int quad = lane >> 4;
  const int col = lane & 15;
  const int bh = blockIdx.y;
  const int q0 = blockIdx.x * 128 + wid * 32;

  const __bf16* qbase = qh + (size_t)bh * S_ * HD_;
  const __bf16* kbase = kh + (size_t)bh * S_ * HD_;
  const __bf16* vbase = vt + (size_t)bh * HD_ * S_;

  // Q fragments held in registers: A[m=col][k=quad*8+j], mi x ks tiles
  bf16x8 aq[2][2];
  for (int mi = 0; mi < 2; ++mi)
    for (int ks = 0; ks < 2; ++ks)
      aq[mi][ks] = *(const bf16x8*)(qbase + (size_t)(q0 + mi * 16 + col) * HD_ +
                                    ks * 32 + quad * 8);

  f32x4 o[2][4] = {};
  float l_state[2][4] = {};

  // staging params (chunk-XOR swizzles for conflict-free ds_read_b128)
  const int krow = t >> 3;                       // K: 16 rows/round... (32/round total)
  const int kgc = (t & 7) ^ ((t >> 3) & 7);
  const int vrow = t >> 4;
  const int vgc = (t & 15) ^ ((t >> 4) & 15);

  const float scale = 0.125f;  // 1/sqrt(64)

  for (int kt = 0; kt < S_ / 128; ++kt) {
    __syncthreads();
    for (int r2 = 0; r2 < 4; ++r2) {
      int row = r2 * 32 + krow;
      gload16(kbase + (size_t)(kt * 128 + row) * HD_ + kgc * 8,
              (char*)lK + row * 128 + (t & 7) * 16);
      int rowv = r2 * 16 + vrow;
      gload16(vbase + (size_t)rowv * S_ + kt * 128 + vgc * 8,
              (char*)lV + rowv * 256 + (t & 15) * 16);
    }
    __syncthreads();

    // S = Q K^T : per wave 32x128 scores
    f32x4 sc[2][8] = {};
    for (int ks = 0; ks < 2; ++ks) {
      for (int nk = 0; nk < 8; ++nk) {
        int row = nk * 16 + col;
        int c = ks * 4 + quad;
        int ch = c ^ (row & 7);
        bf16x8 bkf = *(const bf16x8*)((const char*)lK + row * 128 + ch * 16);
        for (int mi = 0; mi < 2; ++mi)
          sc[mi][nk] = __builtin_amdgcn_mfma_f32_16x16x32_bf16(
              aq[mi][ks], bkf, sc[mi][nk], 0, 0, 0);
      }
    }

    // P = exp(s/8); write P (bf16) to LDS in swizzled layout; accumulate row sums
    for (int mi = 0; mi < 2; ++mi) {
      float rs[4] = {0.f, 0.f, 0.f, 0.f};
      for (int nk = 0; nk < 8; ++nk) {
        for (int r = 0; r < 4; ++r) {
          float e = __expf(sc[mi][nk][r] * scale);
          __bf16 pb = f2bf(e);
          int row = mi * 16 + quad * 4 + r;
          int byteoff = nk * 32 + col * 2;
          int c = byteoff >> 4;
          int ch = c ^ (row & 15);
          *((__bf16*)((char*)&lP[wid][0] + row * 256 + ch * 16 + (byteoff & 15))) = pb;
          rs[r] += (float)pb;
        }
      }
      for (int r = 0; r < 4; ++r) {
        float v = rs[r];
        v += __shfl_xor(v, 1);  v += __shfl_xor(v, 2);
        v += __shfl_xor(v, 4);  v += __shfl_xor(v, 8);
        l_state[mi][r] += v;
      }
    }

    // O += P @ V  (A = P from lP, B = V^T from lV)
    for (int ks2 = 0; ks2 < 4; ++ks2) {
      bf16x8 ap[2];
      for (int mi = 0; mi < 2; ++mi) {
        int row = mi * 16 + col;
        int c = ks2 * 4 + quad;
        int ch = c ^ (row & 15);
        ap[mi] = *(const bf16x8*)((const char*)&lP[wid][0] + row * 256 + ch * 16);
      }
      for (int nj = 0; nj < 4; ++nj) {
        int rowv2 = nj * 16 + col;
        int c2 = ks2 * 4 + quad;
        int ch2 = c2 ^ (rowv2 & 15);
        bf16x8 bvf = *(const bf16x8*)((const char*)lV + rowv2 * 256 + ch2 * 16);
        for (int mi = 0; mi < 2; ++mi)
          o[mi][nj] = __builtin_amdgcn_mfma_f32_16x16x32_bf16(
              ap[mi], bvf, o[mi][nj], 0, 0, 0);
      }
    }
  }

  // finalize: out[b, h*64+col'] += (1/S) * sum_rows (o / l)
  float inv_l[2][4];
  for (int mi = 0; mi < 2; ++mi)
    for (int r = 0; r < 4; ++r) inv_l[mi][r] = 1.0f / l_state[mi][r];
  const int b = bh >> 4;
  const int h = bh & 15;
  for (int nj = 0; nj < 4; ++nj) {
    float s = 0.f;
    for (int mi = 0; mi < 2; ++mi)
      for (int r = 0; r < 4; ++r) s += o[mi][nj][r] * inv_l[mi][r];
    s += __shfl_xor(s, 16);
    s += __shfl_xor(s, 32);
    if (quad == 0)
      atomicAdd(out + (size_t)b * D_ + h * HD_ + nj * 16 + col, s * (1.0f / S_));
  }
}

extern "C" void kernel_launch(void* const* d_in, const int* in_sizes, int n_in,
                              void* d_out, int out_size, void* d_ws, size_t ws_size,
                              hipStream_t stream) {
  const float* x  = (const float*)d_in[0];
  const float* Wq = (const float*)d_in[1];
  const float* bq = (const float*)d_in[2];
  const float* Wk = (const float*)d_in[3];
  const float* bk = (const float*)d_in[4];
  const float* Wv = (const float*)d_in[5];
  const float* bv = (const float*)d_in[6];
  float* out = (float*)d_out;

  char* ws = (char*)d_ws;
  __bf16* xb = (__bf16*)(ws);                       // 8 MB  [4096,1024]
  __bf16* wt = (__bf16*)(ws + ((size_t)8  << 20));  // 6 MB  3x[1024 n][1024 k]
  __bf16* qh = (__bf16*)(ws + ((size_t)14 << 20));  // 8 MB  [B,H,S,HD]
  __bf16* kh = (__bf16*)(ws + ((size_t)22 << 20));  // 8 MB  [B,H,S,HD]
  __bf16* vt = (__bf16*)(ws + ((size_t)30 << 20));  // 8 MB  [B,H,HD,S]

  zero_out_k<<<dim3((B_ * D_ + 255) / 256), dim3(256), 0, stream>>>(out);
  convert_x<<<dim3((B_ * S_ * D_) / 1024), dim3(256), 0, stream>>>(x, xb);
  transpose_w<<<dim3(32, 32, 3), dim3(32, 8), 0, stream>>>(Wq, Wk, Wv, wt);
  gemm_qkv<<<dim3(8, 32, 3), dim3(256), 0, stream>>>(xb, wt, bq, bk, bv, qh, kh, vt);
  attn<<<dim3(S_ / 128, B_ * H_), dim3(256), 0, stream>>>(qh, kh, vt, out);
}